// Round 1
// baseline (102.676 us; speedup 1.0000x reference)
//
#include <hip/hip_runtime.h>
#include <hip/hip_bf16.h>

typedef float f32x4 __attribute__((ext_vector_type(4)));
typedef __bf16 bf16x8 __attribute__((ext_vector_type(8)));

constexpr int B2    = 512;
constexpr int KDIM  = 65536;   // 256*16*16
constexpr int BM    = 256;     // tile M = tile N
constexpr int BK    = 64;
constexpr int NSTEPS = KDIM / BK;   // 1024
constexpr int NTILES = 3;           // (0,0),(0,1),(1,1) — Gram symmetry

// ---- fp32 -> packed 2x bf16 (RNE) ----
__device__ __forceinline__ unsigned pack_bf16x2(float a, float b) {
    __bf16 ha = (__bf16)a, hb = (__bf16)b;
    unsigned short ua, ub;
    __builtin_memcpy(&ua, &ha, 2);
    __builtin_memcpy(&ub, &hb, 2);
    return (unsigned)ua | ((unsigned)ub << 16);
}

// stage 256 rows x 64 cols fp32 -> bf16 LDS tile, XOR-swizzled
__device__ __forceinline__ void stage_tile(__bf16* lds, const float* __restrict__ src,
                                           int k0, int tid) {
#pragma unroll
    for (int it = 0; it < 8; ++it) {
        int r  = it * 32 + (tid >> 4);
        int c4 = (tid & 15) * 4;
        const float4 v = *reinterpret_cast<const float4*>(src + (size_t)r * KDIM + k0 + c4);
        unsigned lo = pack_bf16x2(v.x, v.y);
        unsigned hi = pack_bf16x2(v.z, v.w);
        int byte = r * 128 + (tid & 15) * 8;
        byte ^= (r & 7) << 4;   // swizzle (same XOR on read side)
        *reinterpret_cast<uint2*>(reinterpret_cast<char*>(lds) + byte) = make_uint2(lo, hi);
    }
}

__global__ __launch_bounds__(512, 2) void gemm_partial(const float* __restrict__ X,
                                                       float* __restrict__ partials,
                                                       int ksplit) {
    __shared__ __align__(16) __bf16 ldsA[BM * BK];
    __shared__ __align__(16) __bf16 ldsB[BM * BK];

    int blk   = blockIdx.x;
    int tile  = blk / ksplit;          // 0:(0,0) 1:(0,1) 2:(1,1)
    int split = blk - tile * ksplit;
    int ti = (tile == 2) ? 1 : 0;
    int tj = (tile == 0) ? 0 : 1;
    bool diag = (ti == tj);
    const float* Abase = X + (size_t)ti * 256 * KDIM;
    const float* Bbase = X + (size_t)tj * 256 * KDIM;

    int tid  = threadIdx.x;
    int lane = tid & 63;
    int wave = tid >> 6;     // 8 waves: 2 (M) x 4 (N)
    int wr = wave >> 2;      // 0..1 -> 128 rows each
    int wc = wave & 3;       // 0..3 -> 64 cols each

    int s0 = (int)(((long long)split * NSTEPS) / ksplit);
    int s1 = (int)(((long long)(split + 1) * NSTEPS) / ksplit);

    f32x4 acc[8][4] = {};

    for (int s = s0; s < s1; ++s) {
        int k0 = s * BK;
        __syncthreads();                 // protect LDS from previous iter reads
        stage_tile(ldsA, Abase, k0, tid);
        if (!diag) stage_tile(ldsB, Bbase, k0, tid);
        __syncthreads();
        const __bf16* ldsBp = diag ? ldsA : ldsB;

#pragma unroll
        for (int kk = 0; kk < 2; ++kk) {
            bf16x8 af[8], bfr[4];
            int kbyte = kk * 64 + (lane >> 4) * 16;
#pragma unroll
            for (int mi = 0; mi < 8; ++mi) {
                int row  = wr * 128 + mi * 16 + (lane & 15);
                int byte = (row * 128 + kbyte) ^ ((row & 7) << 4);
                af[mi] = *reinterpret_cast<const bf16x8*>(
                    reinterpret_cast<const char*>(ldsA) + byte);
            }
#pragma unroll
            for (int ni = 0; ni < 4; ++ni) {
                int row  = wc * 64 + ni * 16 + (lane & 15);
                int byte = (row * 128 + kbyte) ^ ((row & 7) << 4);
                bfr[ni] = *reinterpret_cast<const bf16x8*>(
                    reinterpret_cast<const char*>(ldsBp) + byte);
            }
#pragma unroll
            for (int mi = 0; mi < 8; ++mi)
#pragma unroll
                for (int ni = 0; ni < 4; ++ni)
                    acc[mi][ni] = __builtin_amdgcn_mfma_f32_16x16x32_bf16(
                        af[mi], bfr[ni], acc[mi][ni], 0, 0, 0);
        }
    }

    // write this block's 256x256 fp32 partial
    float* out = partials + (size_t)blk * (BM * BM);
    int col   = lane & 15;
    int rquad = (lane >> 4) * 4;
#pragma unroll
    for (int mi = 0; mi < 8; ++mi) {
#pragma unroll
        for (int ni = 0; ni < 4; ++ni) {
            int j = wc * 64 + ni * 16 + col;
#pragma unroll
            for (int v = 0; v < 4; ++v) {
                int i = wr * 128 + mi * 16 + rquad + v;
                out[i * BM + j] = acc[mi][ni][v];
            }
        }
    }
}

// fold split-K partials into full 512x512 C (mirror the off-diag tile)
__global__ __launch_bounds__(256) void reduce_partials(const float* __restrict__ partials,
                                                       float* __restrict__ C, int ksplit) {
    int idx = blockIdx.x * 256 + threadIdx.x;   // over 3*65536
    if (idx >= NTILES * 65536) return;
    int tile = idx >> 16;
    int e    = idx & 65535;
    const float* p = partials + (size_t)tile * ksplit * 65536 + e;
    float sum = 0.f;
    for (int s = 0; s < ksplit; ++s) sum += p[(size_t)s * 65536];
    int i = e >> 8, j = e & 255;
    int gi = (tile == 2) ? 256 + i : i;
    int gj = (tile == 0) ? j : 256 + j;
    C[gi * 512 + gj] = sum;
    if (tile == 1) C[gj * 512 + gi] = sum;   // symmetric mirror
}

// loss = mean( clip(sq_i + sq_j - 2*C_ij, 1e-12) * mask(i,j)^2 )
__global__ __launch_bounds__(256) void loss_kernel(const float* __restrict__ C,
                                                   const int* __restrict__ ranking,
                                                   const int* __restrict__ choice,
                                                   const int* __restrict__ ncp,
                                                   float* __restrict__ out) {
    __shared__ int pos[16];
    __shared__ float wsum[4];
    int i   = blockIdx.x;
    int tid = threadIdx.x;
    if (tid < 16) pos[ranking[i * 16 + tid]] = tid;
    __syncthreads();

    float nc  = (float)(*ncp);
    int   ci  = choice[i];
    float c   = (float)ci;
    float sqi = C[i * 513];   // C[i][i]
    float sum = 0.f;

    for (int j = tid; j < B2; j += 256) {
        int   lbl = ranking[j * 16];        // labels[j] = ranking[j][0]
        int   r   = pos[lbl];               // rank_of_label[i][j]
        float sqj = C[j * 513];
        float d2  = sqi + sqj - 2.f * C[i * 512 + j];
        d2 = fmaxf(d2, 1e-12f);
        float jf = (float)r;
        float m  = (r < ci) ? (1.f - jf / c) : (-(jf - c + 1.f) / (nc - c));
        sum += d2 * m * m;
    }

    for (int off = 32; off > 0; off >>= 1) sum += __shfl_down(sum, off);
    int lane = tid & 63, wave = tid >> 6;
    if (lane == 0) wsum[wave] = sum;
    __syncthreads();
    if (tid == 0) {
        float t = wsum[0] + wsum[1] + wsum[2] + wsum[3];
        atomicAdd(out, t * (1.f / ((float)B2 * (float)B2)));
    }
}

extern "C" void kernel_launch(void* const* d_in, const int* in_sizes, int n_in,
                              void* d_out, int out_size, void* d_ws, size_t ws_size,
                              hipStream_t stream) {
    const float* X        = (const float*)d_in[0];
    const int*   ranking  = (const int*)d_in[1];
    const int*   choice   = (const int*)d_in[2];
    const int*   ncp      = (const int*)d_in[3];
    float*       out      = (float*)d_out;
    float*       ws       = (float*)d_ws;

    // ws layout: C (512*512 f32 = 1 MB) | partials (3*ksplit*256KB)
    int ksplit = 85;   // 3*85 = 255 blocks ~ 1/CU
    {
        size_t need = (size_t)262144 * 4 + (size_t)NTILES * ksplit * 65536 * 4;
        if (need > ws_size) {
            long long avail = (long long)(ws_size / 4) - 262144;
            ksplit = (int)(avail / (NTILES * 65536));
            if (ksplit < 1) ksplit = 1;
        }
    }
    float* C        = ws;
    float* partials = ws + 262144;

    hipMemsetAsync(d_out, 0, sizeof(float), stream);

    gemm_partial<<<dim3(NTILES * ksplit), dim3(512), 0, stream>>>(X, partials, ksplit);

    int relems = NTILES * 65536;
    reduce_partials<<<dim3((relems + 255) / 256), dim3(256), 0, stream>>>(partials, C, ksplit);

    loss_kernel<<<dim3(B2), dim3(256), 0, stream>>>(C, ranking, choice, ncp, out);
}